// Round 10
// baseline (272.122 us; speedup 1.0000x reference)
//
#include <hip/hip_runtime.h>
#include <stdint.h>

typedef unsigned short u16;
typedef unsigned int u32;
typedef unsigned long long u64;
typedef __bf16 bf16x8 __attribute__((ext_vector_type(8)));
typedef float floatx4 __attribute__((ext_vector_type(4)));

#define DEVI static __device__ __forceinline__

DEVI u16 f2bf(float f) {
  uint32_t u = __builtin_bit_cast(uint32_t, f);
  u += 0x7FFFu + ((u >> 16) & 1u);
  return (u16)(u >> 16);
}
DEVI float bf2f(u16 b) { return __builtin_bit_cast(float, (uint32_t)b << 16); }

// async global->LDS 16B (lds dest = wave-uniform base + lane*16)
DEVI void cp16(const u16* g, u16* l) {
#if __has_builtin(__builtin_amdgcn_global_load_lds)
  __builtin_amdgcn_global_load_lds(
      (const __attribute__((address_space(1))) uint32_t*)g,
      (__attribute__((address_space(3))) uint32_t*)l, 16, 0, 0);
#else
  *(uint4*)l = *(const uint4*)g;
#endif
}

// ---- workspace layout (bytes) ----
static constexpr size_t OFF_CORRP = 0;                                   // f32 [cb4][m][n][65][65]
static constexpr size_t OFF_SATT  = OFF_CORRP + (size_t)4*270400*4;      // bf16 [m][cb][y][x][c8]
static constexpr size_t OFF_GRDP  = OFF_SATT + (size_t)8*4*96*96*8*2;    // bf16 [cb][i*32+j][col16][c8]
static constexpr size_t OFF_S2    = OFF_GRDP + (size_t)4*1024*16*8*2;    // f32 [8][96][96]
static constexpr size_t OFF_PART  = OFF_S2   + (size_t)73728*4;          // f32 [8][65][65]
static constexpr size_t OFF_NRMP  = OFF_PART + (size_t)33800*4;          // f32 sat nrm partials [8][96]
static constexpr size_t OFF_GNRM  = OFF_NRMP + 768*4;                    // f32 grd nrm2 [8]
static constexpr size_t OFF_MASK  = OFF_GNRM + 32;                       // f32 [8][1024]
static constexpr size_t OFF_CNT   = OFF_MASK + (size_t)8192*4;           // u32 convcnt[8] + partcnt[8]

// ---- K1: blocks 0..767: one sat row -> bf16 channels-last + s2 + norm partial.
//          blocks 768..775: grd pack. block 776: zero counters.
__global__ __launch_bounds__(256) void k_prep(
    const float* __restrict__ grd, const float* __restrict__ sat,
    u16* __restrict__ sTh, u16* __restrict__ gP,
    float* __restrict__ s2, float* __restrict__ nrmp,
    float* __restrict__ gnrm, float* __restrict__ gmask,
    u32* __restrict__ cnts) {
  __shared__ float L[32*100];
  __shared__ float red[256];
  const int t = threadIdx.x;
  if (blockIdx.x < 768) {
    const int m = blockIdx.x / 96, y = blockIdx.x - (blockIdx.x / 96) * 96;
    #pragma unroll
    for (int k = 0; k < 3; ++k) {
      const int idx = k*256 + t;
      const int c = idx / 24, xq = idx - c*24;
      const float4 v = *(const float4*)(sat + (((size_t)m*32 + c)*128 + (16+y))*128 + 16 + xq*4);
      *(float4*)(&L[c*100 + xq*4]) = v;
    }
    __syncthreads();
    float ss = 0.f;
    if (t < 96) {
      #pragma unroll
      for (int c = 0; c < 32; ++c) { const float v = L[c*100 + t]; ss += v*v; }
      s2[(size_t)m*9216 + y*96 + t] = ss;
    }
    red[t] = ss; __syncthreads();
    for (int s = 128; s > 0; s >>= 1) { if (t < s) red[t] += red[t+s]; __syncthreads(); }
    if (t == 0) nrmp[m*96 + y] = red[0];
    for (int idx = t; idx < 384; idx += 256) {
      const int cb = idx / 96, x = idx - cb*96;
      union { u16 us[8]; uint4 v4; } P;
      #pragma unroll
      for (int e = 0; e < 8; ++e) P.us[e] = f2bf(L[(cb*8+e)*100 + x]);
      *(uint4*)(&sTh[(((size_t)m*4+cb)*9216 + (size_t)y*96 + x)*8]) = P.v4;
    }
  } else if (blockIdx.x == 776) {
    if (t < 16) cnts[t] = 0u;      // convcnt[8] + partcnt[8]
  } else {
    const int n = blockIdx.x - 768;
    float nn = 0.f, scs[4];
    #pragma unroll
    for (int it = 0; it < 4; ++it) {
      const int pidx = it*256 + t;
      float vals[32]; float sc = 0.f;
      #pragma unroll
      for (int c = 0; c < 32; ++c) {
        const float v = grd[((size_t)n*32 + c)*1024 + pidx];
        vals[c] = v; sc += v; nn += v*v;
      }
      scs[it] = sc;
      #pragma unroll
      for (int cb = 0; cb < 4; ++cb) {
        union { u16 us[8]; uint4 v4; } ph, pl;
        #pragma unroll
        for (int e = 0; e < 8; ++e) {
          const float v = vals[cb*8+e];
          const u16 h = f2bf(v); ph.us[e] = h; pl.us[e] = f2bf(v - bf2f(h));
        }
        const size_t o = ((size_t)cb*1024 + pidx)*128;
        *(uint4*)(&gP[o + (size_t)n*8])     = ph.v4;
        *(uint4*)(&gP[o + (size_t)(n+8)*8]) = pl.v4;
      }
    }
    red[t] = nn; __syncthreads();
    for (int s = 128; s > 0; s >>= 1) { if (t < s) red[t] += red[t+s]; __syncthreads(); }
    const float gn = fmaxf(sqrtf(red[0]), 1e-12f);
    if (t == 0) gnrm[n] = red[0];
    const float thr = 1e-6f * gn;
    #pragma unroll
    for (int it = 0; it < 4; ++it)
      gmask[n*1024 + it*256 + t] = (fabsf(scs[it]) > thr) ? 1.f : 0.f;
  }
}

// ---- K2 (fused): blocks 0..895 main conv; 896..1055 edge x=64; 1056..1127
// part+post workers. Conv blocks release convcnt[m] (store -> threadfence ->
// atomicAdd); post workers spin-acquire, then normalize/max/refine/mask. ----
__global__ __launch_bounds__(256, 3) void k_conv(
    const u16* __restrict__ satT, const u16* __restrict__ gP,
    const float* __restrict__ s2, float* __restrict__ corr_p,
    float* __restrict__ part, const float* __restrict__ nrmp,
    const float* __restrict__ gnrm, const int* __restrict__ tm,
    const float* __restrict__ grd, const float* __restrict__ sat,
    const float* __restrict__ gmask, u32* __restrict__ cnts,
    float* __restrict__ out)
{
  __shared__ __align__(16) u16 patch[41*48*8];   // 31488 B
  __shared__ float sbest; __shared__ int sbix;
  __shared__ u32 fcnt;

  const int bi = blockIdx.x;
  const int tid = threadIdx.x;

  if (bi >= 1056) {
    // ======== part + post workers ========
    float* F = (float*)patch;
    const int pb = bi - 1056;
    const int pm = pb / 9, j = pb - pm*9;
    {
      float* S  = F;                    // [<=40][96]
      float* HS = F + 40*96;            // [<=39][65]
      const int ysl = j*8;
      const int nrows = (65 - ysl) < 8 ? (65 - ysl) : 8;
      const int scnt  = (96 - ysl) < 40 ? (96 - ysl) : 40;
      for (int idx = tid; idx < scnt*96; idx += 256)
        S[idx] = s2[(size_t)pm*9216 + (size_t)ysl*96 + idx];
      __syncthreads();
      const int hrows = nrows + 31;
      for (int idx = tid; idx < hrows*65; idx += 256) {
        const int r = idx / 65, xo = idx - r*65;
        const float* p = &S[r*96 + xo];
        float s = 0.f;
        #pragma unroll
        for (int jj = 0; jj < 32; ++jj) s += p[jj];
        HS[idx] = s;
      }
      __syncthreads();
      for (int idx = tid; idx < nrows*65; idx += 256) {
        const int r = idx / 65, xo = idx - r*65;
        float s = 0.f;
        #pragma unroll
        for (int i = 0; i < 32; ++i) s += HS[(r+i)*65 + xo];
        part[(size_t)pm*4225 + (size_t)(ysl+r)*65 + xo] = s;
      }
    }
    __threadfence();                    // release part stores
    __syncthreads();
    if (tid == 0) atomicAdd(&cnts[8+pm], 1u);
    if (j >= 8) return;

    const int n = j;
    // acquire: wait for all conv blocks of pm (132) and all 9 part slabs
    if (tid == 0) {
      while (atomicAdd(&cnts[pm], 0u) < 132u || atomicAdd(&cnts[8+pm], 0u) < 9u)
        __builtin_amdgcn_s_sleep(8);
    }
    __syncthreads();
    __threadfence();

    float* vbuf = F;                    // 4225 f
    float* red  = F + 4608;             // 256 f
    int*  fidx  = (int*)(F + 4880);     // 128 i

    red[tid] = (tid < 96) ? nrmp[pm*96 + tid] : 0.f;
    __syncthreads();
    for (int s = 128; s > 0; s >>= 1) { if (tid < s) red[tid] += red[tid+s]; __syncthreads(); }
    const float srn = 1.f / fmaxf(sqrtf(red[0]), 1e-12f);
    const float grn = 1.f / fmaxf(sqrtf(gnrm[n]), 1e-12f);
    const float cscale = grn * srn, pscale = srn * srn;
    const int method = tm[0];
    const bool diag = (pm == n);
    const float* cp = corr_p + (size_t)(pm*8+n)*4225;
    const float* pp = part + (size_t)pm*4225;
    __syncthreads();                    // red reduce done before vbuf writes overlap? (vbuf disjoint from red)

    float bestv = -3.4e38f;
    for (int idx = tid; idx < 4225; idx += 256) {
      const float c = cp[idx] + cp[idx+270400] + cp[idx+540800] + cp[idx+811200];
      const float pt = pp[idx] * pscale;
      float denom = (method == 0) ? sqrtf(pt) : pt;
      denom = fmaxf(denom, 1e-12f);
      const float v = c * cscale / denom;
      if (diag) vbuf[idx] = v;
      bestv = fmaxf(bestv, v);
    }
    __syncthreads();
    red[tid] = bestv; __syncthreads();
    for (int s = 128; s > 0; s >>= 1) { if (tid < s) red[tid] = fmaxf(red[tid], red[tid+s]); __syncthreads(); }
    if (tid == 0) out[pm*8 + n] = red[0];
    if (!diag) return;
    const float vmax = red[0];

    // candidates within 3e-3 (>> 2-term split error ~1e-5)
    if (tid == 0) { fcnt = 0u; sbest = -3.4e38f; sbix = 0x7FFFFFFF; }
    __syncthreads();
    const float thr = vmax - 3e-3f;
    for (int idx = tid; idx < 4225; idx += 256)
      if (vbuf[idx] >= thr) { const u32 s = atomicAdd(&fcnt, 1u); if (s < 128) fidx[s] = idx; }
    __syncthreads();
    int nf = (int)fcnt; if (nf > 128) nf = 128; if (nf < 1) nf = 1;

    const int c = tid >> 3, s8 = tid & 7;
    for (int ci = 0; ci < nf; ++ci) {
      const int idx = fidx[ci];
      const int y = idx / 65, x = idx - y*65;
      float a = 0.f;
      #pragma unroll
      for (int ii = 0; ii < 4; ++ii) {
        const int i = s8 + ii*8;
        const float* gr = grd + ((size_t)n*32 + c)*1024 + i*32;
        const float* sr = sat + (((size_t)n*32 + c)*128 + (16 + y + i))*128 + (16 + x);
        #pragma unroll
        for (int jj = 0; jj < 32; ++jj) a += gr[jj] * sr[jj];
      }
      red[tid] = a; __syncthreads();
      for (int st = 128; st > 0; st >>= 1) { if (tid < st) red[tid] += red[tid+st]; __syncthreads(); }
      if (tid == 0) {
        const float pt = pp[idx] * pscale;
        float denom = (method == 0) ? sqrtf(pt) : pt;
        denom = fmaxf(denom, 1e-12f);
        const float v = red[0] * cscale / denom;
        if (v > sbest || (v == sbest && idx < sbix)) { sbest = v; sbix = idx; }
      }
      __syncthreads();
    }
    const int bix = sbix;
    const int ph = bix / 65, pw = bix - (bix/65)*65;
    for (int p = tid; p < 9216; p += 256) {
      const int yy = p / 96, xx = p - yy*96;
      float val = 0.f;
      if (yy >= ph && yy < ph+32 && xx >= pw && xx < pw+32)
        val = gmask[n*1024 + (yy-ph)*32 + (xx-pw)];
      out[64 + (size_t)n*9216 + p] = val;
    }
    return;
  }

  const int wave = tid >> 6, lane = tid & 63;
  const int pr = lane & 15, q = lane >> 4;

  if (bi >= 896) {             // ---- edge blocks: x = 64 column ----
    const int e = bi - 896;
    const int cb = e & 3;
    const int yt = (e >> 2) % 5;
    const int m  = e / 20;
    const int ybase = yt * 13;
    const size_t rowbase = ((size_t)(m*4 + cb) * 96 + ybase) * 96;
    for (int k = tid; k < 44*32; k += 256) {
      const int rho = k >> 5, px = k & 31;
      cp16(&satT[(rowbase + (size_t)rho*96 + 64 + px)*8], &patch[(size_t)k*8]);
    }
    asm volatile("s_waitcnt vmcnt(0)" ::: "memory");
    __syncthreads();
    const int prc = pr < 13 ? pr : 12;
    floatx4 acc = (floatx4){0.f, 0.f, 0.f, 0.f};
    #pragma unroll
    for (int jbi = 0; jbi < 2; ++jbi) {
      const int jb = wave*2 + jbi;
      const int px_e = jb*4 + q;
      const u16* bp = gP + ((size_t)cb*1024 + (size_t)(jb*4+q))*128 + (size_t)pr*8;
      uint4 Br[8];
      #pragma unroll
      for (int ii = 0; ii < 8; ++ii) Br[ii] = *(const uint4*)(bp + (size_t)ii*4096);
      uint4 Ah[8];
      #pragma unroll
      for (int s = 0; s < 6; ++s)
        Ah[s] = *(const uint4*)(&patch[((size_t)(prc + s)*32 + px_e)*8]);
      #pragma unroll
      for (int i = 0; i < 32; ++i) {
        if (i < 26)
          Ah[(i+6)&7] = *(const uint4*)(&patch[((size_t)(prc + i + 6)*32 + px_e)*8]);
        const bf16x8 bf = __builtin_bit_cast(bf16x8, Br[i&7]);
        if (i < 24)
          Br[(i+8)&7] = *(const uint4*)(bp + (size_t)(i+8)*4096);
        acc = __builtin_amdgcn_mfma_f32_16x16x32_bf16(
            __builtin_bit_cast(bf16x8, Ah[i&7]), bf, acc, 0, 0, 0);
      }
    }
    float v4[4];
    #pragma unroll
    for (int k = 0; k < 4; ++k) v4[k] = acc[k] + __shfl_xor(acc[k], 8);
    __syncthreads();
    float* red = (float*)patch;
    #pragma unroll
    for (int k = 0; k < 4; ++k) red[((size_t)wave*64 + lane)*5 + k] = v4[k];
    __syncthreads();
    if (wave == 0 && pr < 8) {
      #pragma unroll
      for (int k = 0; k < 4; ++k) {
        const int yoff = q*4 + k;
        if (yoff < 13) {
          float s = 0.f;
          #pragma unroll
          for (int w = 0; w < 4; ++w) s += red[((size_t)w*64 + lane)*5 + k];
          corr_p[(size_t)cb*270400 + ((size_t)(m*8+pr)*65 + (ybase+yoff))*65 + 64] = s;
        }
      }
    }
    __threadfence();                   // release corr stores
    __syncthreads();
    if (tid == 0) atomicAdd(&cnts[m], 1u);
    return;
  }

  // ---- main conv blocks ----
  int b = bi;
  const int cb = b & 3; b >>= 2;
  const int xt = b & 3; b >>= 2;
  const int yt = b % 7;
  const int m  = b / 7;
  const int x0 = xt*16;

  if (yt < 6) {
    // ======== 10-row tile, rows y0..y0+9, patch 41 rows ========
    const int y0 = yt*10;
    const size_t rowbase = ((size_t)(m*4 + cb) * 96 + y0) * 96;
    for (int k = tid; k < 41*48; k += 256) {
      const int rho = k / 48, px = k - (k/48)*48;
      cp16(&satT[(rowbase + (size_t)rho*96 + x0 + px)*8], &patch[(size_t)k*8]);
    }
    asm volatile("s_waitcnt vmcnt(0)" ::: "memory");
    __syncthreads();

    floatx4 acc[10];
    #pragma unroll
    for (int r = 0; r < 10; ++r) acc[r] = (floatx4){0.f, 0.f, 0.f, 0.f};

    #pragma unroll
    for (int jbi = 0; jbi < 2; ++jbi) {
      const int jb = wave*2 + jbi;
      const int apx = pr + jb*4 + q;
      const u16* bp = gP + ((size_t)cb*1024 + (size_t)(jb*4+q))*128 + (size_t)pr*8;

      uint4 Br[8];
      #pragma unroll
      for (int ii = 0; ii < 8; ++ii) Br[ii] = *(const uint4*)(bp + (size_t)ii*4096);
      uint4 Ah[12];
      #pragma unroll
      for (int s = 0; s < 12; ++s) Ah[s] = *(const uint4*)(&patch[((size_t)s*48 + apx)*8]);

      #pragma unroll
      for (int i = 0; i < 32; ++i) {
        const bf16x8 bf = __builtin_bit_cast(bf16x8, Br[i&7]);
        if (i < 24)
          Br[(i+8)&7] = *(const uint4*)(bp + (size_t)(i+8)*4096);
        #pragma unroll
        for (int r = 0; r < 10; ++r)
          acc[r] = __builtin_amdgcn_mfma_f32_16x16x32_bf16(
              __builtin_bit_cast(bf16x8, Ah[(i+r)%12]), bf, acc[r], 0, 0, 0);
        if (i < 29)
          Ah[(i+12)%12] = *(const uint4*)(&patch[((size_t)(i+12)*48 + apx)*8]);
      }
    }

    float vals[40];
    #pragma unroll
    for (int r = 0; r < 10; ++r)
      #pragma unroll
      for (int k = 0; k < 4; ++k)
        vals[r*4+k] = acc[r][k] + __shfl_xor(acc[r][k], 8);

    float* red = (float*)patch;
    #pragma unroll
    for (int half = 0; half < 2; ++half) {
      __syncthreads();
      #pragma unroll
      for (int u = 0; u < 20; ++u) red[((size_t)wave*64 + lane)*21 + u] = vals[half*20 + u];
      __syncthreads();
      if (wave == 0 && pr < 8) {
        #pragma unroll
        for (int r = 0; r < 5; ++r) {
          #pragma unroll
          for (int k = 0; k < 4; ++k) {
            const int x = x0 + q*4 + k;
            float s = 0.f;
            #pragma unroll
            for (int w = 0; w < 4; ++w) s += red[((size_t)w*64 + lane)*21 + r*4 + k];
            corr_p[(size_t)cb*270400 + ((size_t)(m*8+pr)*65 + (y0 + half*5 + r))*65 + x] = s;
          }
        }
      }
    }
  } else {
    // ======== 5-row tile, rows 60..64 ========
    const int y0 = 60;
    const size_t rowbase = ((size_t)(m*4 + cb) * 96 + y0) * 96;
    for (int k = tid; k < 36*48; k += 256) {
      const int rho = k / 48, px = k - (k/48)*48;
      cp16(&satT[(rowbase + (size_t)rho*96 + x0 + px)*8], &patch[(size_t)k*8]);
    }
    asm volatile("s_waitcnt vmcnt(0)" ::: "memory");
    __syncthreads();

    floatx4 acc[5];
    #pragma unroll
    for (int r = 0; r < 5; ++r) acc[r] = (floatx4){0.f, 0.f, 0.f, 0.f};

    #pragma unroll
    for (int jbi = 0; jbi < 2; ++jbi) {
      const int jb = wave*2 + jbi;
      const int apx = pr + jb*4 + q;
      const u16* bp = gP + ((size_t)cb*1024 + (size_t)(jb*4+q))*128 + (size_t)pr*8;

      uint4 Br[8];
      #pragma unroll
      for (int ii = 0; ii < 8; ++ii) Br[ii] = *(const uint4*)(bp + (size_t)ii*4096);
      uint4 Ah[8];
      #pragma unroll
      for (int s = 0; s < 6; ++s) Ah[s] = *(const uint4*)(&patch[((size_t)s*48 + apx)*8]);

      #pragma unroll
      for (int i = 0; i < 32; ++i) {
        if (i < 30)
          Ah[(i+6)&7] = *(const uint4*)(&patch[((size_t)(i+6)*48 + apx)*8]);
        const bf16x8 bf = __builtin_bit_cast(bf16x8, Br[i&7]);
        if (i < 24)
          Br[(i+8)&7] = *(const uint4*)(bp + (size_t)(i+8)*4096);
        #pragma unroll
        for (int r = 0; r < 5; ++r)
          acc[r] = __builtin_amdgcn_mfma_f32_16x16x32_bf16(
              __builtin_bit_cast(bf16x8, Ah[(i+r)&7]), bf, acc[r], 0, 0, 0);
      }
    }

    float vals[20];
    #pragma unroll
    for (int r = 0; r < 5; ++r)
      #pragma unroll
      for (int k = 0; k < 4; ++k)
        vals[r*4+k] = acc[r][k] + __shfl_xor(acc[r][k], 8);

    __syncthreads();
    float* red = (float*)patch;
    #pragma unroll
    for (int u = 0; u < 20; ++u) red[((size_t)wave*64 + lane)*21 + u] = vals[u];
    __syncthreads();
    if (wave == 0 && pr < 8) {
      #pragma unroll
      for (int r = 0; r < 5; ++r) {
        #pragma unroll
        for (int k = 0; k < 4; ++k) {
          const int x = x0 + q*4 + k;
          float s = 0.f;
          #pragma unroll
          for (int w = 0; w < 4; ++w) s += red[((size_t)w*64 + lane)*21 + r*4 + k];
          corr_p[(size_t)cb*270400 + ((size_t)(m*8+pr)*65 + (y0+r))*65 + x] = s;
        }
      }
    }
  }
  __threadfence();                     // release corr stores
  __syncthreads();
  if (tid == 0) atomicAdd(&cnts[m], 1u);
}

extern "C" void kernel_launch(void* const* d_in, const int* in_sizes, int n_in,
                              void* d_out, int out_size, void* d_ws, size_t ws_size,
                              hipStream_t stream) {
  const float* grd = (const float*)d_in[0];
  const float* sat = (const float*)d_in[1];
  const int*   tm  = (const int*)d_in[2];
  float* out = (float*)d_out;
  char* ws = (char*)d_ws;

  float* corrp = (float*)(ws + OFF_CORRP);
  u16*   sTh   = (u16*)(ws + OFF_SATT);
  u16*   gP    = (u16*)(ws + OFF_GRDP);
  float* s2    = (float*)(ws + OFF_S2);
  float* part  = (float*)(ws + OFF_PART);
  float* nrmp  = (float*)(ws + OFF_NRMP);
  float* gnrm  = (float*)(ws + OFF_GNRM);
  float* gmask = (float*)(ws + OFF_MASK);
  u32*   cnts  = (u32*)(ws + OFF_CNT);

  k_prep<<<777,  256, 0, stream>>>(grd, sat, sTh, gP, s2, nrmp, gnrm, gmask, cnts);
  k_conv<<<1128, 256, 0, stream>>>(sTh, gP, s2, corrp, part, nrmp, gnrm, tm,
                                   grd, sat, gmask, cnts, out);
}

// Round 11
// 147.193 us; speedup vs baseline: 1.8487x; 1.8487x over previous
//
#include <hip/hip_runtime.h>
#include <stdint.h>

typedef unsigned short u16;
typedef unsigned int u32;
typedef unsigned long long u64;
typedef __bf16 bf16x8 __attribute__((ext_vector_type(8)));
typedef float floatx4 __attribute__((ext_vector_type(4)));

#define DEVI static __device__ __forceinline__

DEVI u16 f2bf(float f) {
  uint32_t u = __builtin_bit_cast(uint32_t, f);
  u += 0x7FFFu + ((u >> 16) & 1u);
  return (u16)(u >> 16);
}
DEVI float bf2f(u16 b) { return __builtin_bit_cast(float, (uint32_t)b << 16); }

// order-preserving float<->uint encoding
DEVI u32 encf(float f) {
  u32 u = __builtin_bit_cast(u32, f);
  return (u >> 31) ? ~u : (u | 0x80000000u);
}
DEVI float decf(u32 e) {
  u32 u = (e >> 31) ? (e & 0x7FFFFFFFu) : ~e;
  return __builtin_bit_cast(float, u);
}

// async global->LDS 16B (lds dest = wave-uniform base + lane*16)
DEVI void cp16(const u16* g, u16* l) {
#if __has_builtin(__builtin_amdgcn_global_load_lds)
  __builtin_amdgcn_global_load_lds(
      (const __attribute__((address_space(1))) uint32_t*)g,
      (__attribute__((address_space(3))) uint32_t*)l, 16, 0, 0);
#else
  *(uint4*)l = *(const uint4*)g;
#endif
}

// ---- workspace layout (bytes) ----
static constexpr size_t OFF_CORRP = 0;                                   // f32 [cb4][m][n][65][65]
static constexpr size_t OFF_SATT  = OFF_CORRP + (size_t)4*270400*4;      // bf16 [m][cb][y][x][c8]
static constexpr size_t OFF_GRDP  = OFF_SATT + (size_t)8*4*96*96*8*2;    // bf16 [cb][i*32+j][col16][c8]
static constexpr size_t OFF_S2    = OFF_GRDP + (size_t)4*1024*16*8*2;    // f32 [8][96][96]
static constexpr size_t OFF_PART  = OFF_S2   + (size_t)73728*4;          // f32 [8][65][65]
static constexpr size_t OFF_NRMP  = OFF_PART + (size_t)33800*4;          // f32 sat nrm partials [8][96]
static constexpr size_t OFF_GNRM  = OFF_NRMP + 768*4;                    // f32 grd nrm2 [8]
static constexpr size_t OFF_MASK  = OFF_GNRM + 32;                       // f32 [8][1024]
static constexpr size_t OFF_PMAX  = OFF_MASK + (size_t)8192*4;           // u32 enc chunk max [320]
static constexpr size_t OFF_CNT   = OFF_PMAX + 320*4;                    // u32 grpcnt[64] + candcnt[8]
static constexpr size_t OFF_CAND  = OFF_CNT  + 512;                      // u64 cand[8][128]

// ---- K1: blocks 0..767: one sat row -> bf16 channels-last + s2 + norm partial.
//          blocks 768..775: grd pack. block 776: zero counters.
__global__ __launch_bounds__(256) void k_prep(
    const float* __restrict__ grd, const float* __restrict__ sat,
    u16* __restrict__ sTh, u16* __restrict__ gP,
    float* __restrict__ s2, float* __restrict__ nrmp,
    float* __restrict__ gnrm, float* __restrict__ gmask,
    u32* __restrict__ cnts) {
  __shared__ float L[32*100];
  __shared__ float red[256];
  const int t = threadIdx.x;
  if (blockIdx.x < 768) {
    const int m = blockIdx.x / 96, y = blockIdx.x - (blockIdx.x / 96) * 96;
    #pragma unroll
    for (int k = 0; k < 3; ++k) {
      const int idx = k*256 + t;
      const int c = idx / 24, xq = idx - c*24;
      const float4 v = *(const float4*)(sat + (((size_t)m*32 + c)*128 + (16+y))*128 + 16 + xq*4);
      *(float4*)(&L[c*100 + xq*4]) = v;
    }
    __syncthreads();
    float ss = 0.f;
    if (t < 96) {
      #pragma unroll
      for (int c = 0; c < 32; ++c) { const float v = L[c*100 + t]; ss += v*v; }
      s2[(size_t)m*9216 + y*96 + t] = ss;
    }
    red[t] = ss; __syncthreads();
    for (int s = 128; s > 0; s >>= 1) { if (t < s) red[t] += red[t+s]; __syncthreads(); }
    if (t == 0) nrmp[m*96 + y] = red[0];
    for (int idx = t; idx < 384; idx += 256) {
      const int cb = idx / 96, x = idx - cb*96;
      union { u16 us[8]; uint4 v4; } P;
      #pragma unroll
      for (int e = 0; e < 8; ++e) P.us[e] = f2bf(L[(cb*8+e)*100 + x]);
      *(uint4*)(&sTh[(((size_t)m*4+cb)*9216 + (size_t)y*96 + x)*8]) = P.v4;
    }
  } else if (blockIdx.x == 776) {
    if (t < 72) cnts[t] = 0u;
  } else {
    const int n = blockIdx.x - 768;
    float nn = 0.f, scs[4];
    #pragma unroll
    for (int it = 0; it < 4; ++it) {
      const int pidx = it*256 + t;
      float vals[32]; float sc = 0.f;
      #pragma unroll
      for (int c = 0; c < 32; ++c) {
        const float v = grd[((size_t)n*32 + c)*1024 + pidx];
        vals[c] = v; sc += v; nn += v*v;
      }
      scs[it] = sc;
      #pragma unroll
      for (int cb = 0; cb < 4; ++cb) {
        union { u16 us[8]; uint4 v4; } ph, pl;
        #pragma unroll
        for (int e = 0; e < 8; ++e) {
          const float v = vals[cb*8+e];
          const u16 h = f2bf(v); ph.us[e] = h; pl.us[e] = f2bf(v - bf2f(h));
        }
        const size_t o = ((size_t)cb*1024 + pidx)*128;
        *(uint4*)(&gP[o + (size_t)n*8])     = ph.v4;
        *(uint4*)(&gP[o + (size_t)(n+8)*8]) = pl.v4;
      }
    }
    red[t] = nn; __syncthreads();
    for (int s = 128; s > 0; s >>= 1) { if (t < s) red[t] += red[t+s]; __syncthreads(); }
    const float gn = fmaxf(sqrtf(red[0]), 1e-12f);
    if (t == 0) gnrm[n] = red[0];
    const float thr = 1e-6f * gn;
    #pragma unroll
    for (int it = 0; it < 4; ++it)
      gmask[n*1024 + it*256 + t] = (fabsf(scs[it]) > thr) ? 1.f : 0.f;
  }
}

// ---- K2: blocks 0..71: window-sum of s2 -> part (FIRST: off the critical tail).
//          blocks 72..967: main conv (m8,yt7,xt4,cb4); yt<6: 10-row, yt=6: 5-row.
//          blocks 968..1127: edge conv x=64.
__global__ __launch_bounds__(256, 3) void k_conv(
    const u16* __restrict__ satT, const u16* __restrict__ gP,
    const float* __restrict__ s2, float* __restrict__ corr_p,
    float* __restrict__ part)
{
  __shared__ __align__(16) u16 patch[41*48*8];   // 31488 B

  const int bi = blockIdx.x;
  const int tid = threadIdx.x;

  if (bi < 72) {               // ---- part blocks (dispatched first) ----
    float* S  = (float*)patch;          // [<=40][96]
    float* HS = S + 40*96;              // [<=39][65]  (25500 B <= 31488)
    const int pm = bi / 9, ysl = (bi - pm*9)*8;
    const int nrows = (65 - ysl) < 8 ? (65 - ysl) : 8;
    const int scnt  = (96 - ysl) < 40 ? (96 - ysl) : 40;
    for (int idx = tid; idx < scnt*96; idx += 256)
      S[idx] = s2[(size_t)pm*9216 + (size_t)ysl*96 + idx];
    __syncthreads();
    const int hrows = nrows + 31;
    for (int idx = tid; idx < hrows*65; idx += 256) {
      const int r = idx / 65, xo = idx - r*65;
      const float* p = &S[r*96 + xo];
      float s = 0.f;
      #pragma unroll
      for (int j = 0; j < 32; ++j) s += p[j];
      HS[idx] = s;
    }
    __syncthreads();
    for (int idx = tid; idx < nrows*65; idx += 256) {
      const int r = idx / 65, xo = idx - r*65;
      float s = 0.f;
      #pragma unroll
      for (int i = 0; i < 32; ++i) s += HS[(r+i)*65 + xo];
      part[(size_t)pm*4225 + (size_t)(ysl+r)*65 + xo] = s;
    }
    return;
  }

  const int wave = tid >> 6, lane = tid & 63;
  const int pr = lane & 15, q = lane >> 4;

  if (bi >= 968) {             // ---- edge blocks: x = 64 column (r8-proven) ----
    const int e = bi - 968;
    const int cb = e & 3;
    const int yt = (e >> 2) % 5;
    const int m  = e / 20;
    const int ybase = yt * 13;
    const size_t rowbase = ((size_t)(m*4 + cb) * 96 + ybase) * 96;
    for (int k = tid; k < 44*32; k += 256) {
      const int rho = k >> 5, px = k & 31;
      cp16(&satT[(rowbase + (size_t)rho*96 + 64 + px)*8], &patch[(size_t)k*8]);
    }
    asm volatile("s_waitcnt vmcnt(0)" ::: "memory");
    __syncthreads();
    const int prc = pr < 13 ? pr : 12;   // rows 13-15 duplicate row 12 (D rows discarded)
    floatx4 acc = (floatx4){0.f, 0.f, 0.f, 0.f};
    #pragma unroll
    for (int jbi = 0; jbi < 2; ++jbi) {
      const int jb = wave*2 + jbi;
      const int px_e = jb*4 + q;
      const u16* bp = gP + ((size_t)cb*1024 + (size_t)(jb*4+q))*128 + (size_t)pr*8;
      uint4 Br[8];
      #pragma unroll
      for (int ii = 0; ii < 8; ++ii) Br[ii] = *(const uint4*)(bp + (size_t)ii*4096);
      uint4 Ah[8];
      #pragma unroll
      for (int s = 0; s < 6; ++s)
        Ah[s] = *(const uint4*)(&patch[((size_t)(prc + s)*32 + px_e)*8]);
      #pragma unroll
      for (int i = 0; i < 32; ++i) {
        if (i < 26)
          Ah[(i+6)&7] = *(const uint4*)(&patch[((size_t)(prc + i + 6)*32 + px_e)*8]);
        const bf16x8 bf = __builtin_bit_cast(bf16x8, Br[i&7]);
        if (i < 24)
          Br[(i+8)&7] = *(const uint4*)(bp + (size_t)(i+8)*4096);
        acc = __builtin_amdgcn_mfma_f32_16x16x32_bf16(
            __builtin_bit_cast(bf16x8, Ah[i&7]), bf, acc, 0, 0, 0);
      }
    }
    float v4[4];
    #pragma unroll
    for (int k = 0; k < 4; ++k) v4[k] = acc[k] + __shfl_xor(acc[k], 8);
    __syncthreads();
    float* red = (float*)patch;
    #pragma unroll
    for (int k = 0; k < 4; ++k) red[((size_t)wave*64 + lane)*5 + k] = v4[k];
    __syncthreads();
    if (wave == 0 && pr < 8) {
      #pragma unroll
      for (int k = 0; k < 4; ++k) {
        const int yoff = q*4 + k;
        if (yoff < 13) {
          float s = 0.f;
          #pragma unroll
          for (int w = 0; w < 4; ++w) s += red[((size_t)w*64 + lane)*5 + k];
          corr_p[(size_t)cb*270400 + ((size_t)(m*8+pr)*65 + (ybase+yoff))*65 + 64] = s;
        }
      }
    }
    return;
  }

  // ---- main conv blocks ----
  int b = bi - 72;
  const int cb = b & 3; b >>= 2;
  const int xt = b & 3; b >>= 2;
  const int yt = b % 7;
  const int m  = b / 7;
  const int x0 = xt*16;

  if (yt < 6) {
    // ======== 10-row tile, rows y0..y0+9, patch 41 rows ========
    const int y0 = yt*10;
    const size_t rowbase = ((size_t)(m*4 + cb) * 96 + y0) * 96;
    for (int k = tid; k < 41*48; k += 256) {
      const int rho = k / 48, px = k - (k/48)*48;
      cp16(&satT[(rowbase + (size_t)rho*96 + x0 + px)*8], &patch[(size_t)k*8]);
    }
    asm volatile("s_waitcnt vmcnt(0)" ::: "memory");
    __syncthreads();

    floatx4 acc[10];
    #pragma unroll
    for (int r = 0; r < 10; ++r) acc[r] = (floatx4){0.f, 0.f, 0.f, 0.f};

    #pragma unroll
    for (int jbi = 0; jbi < 2; ++jbi) {
      const int jb = wave*2 + jbi;
      const int apx = pr + jb*4 + q;                       // <= 46
      const u16* bp = gP + ((size_t)cb*1024 + (size_t)(jb*4+q))*128 + (size_t)pr*8;

      uint4 Br[8];
      #pragma unroll
      for (int ii = 0; ii < 8; ++ii) Br[ii] = *(const uint4*)(bp + (size_t)ii*4096);
      // Ah ring depth 12: init rows 0..11; at iter i prefetch row i+12 into slot
      // i%12 AFTER the MFMA chain (row-i read precedes in source: WAR-safe).
      // Coverage: rows 12..40 prefetched at i=0..28; max row used = 31+9 = 40.
      uint4 Ah[12];
      #pragma unroll
      for (int s = 0; s < 12; ++s) Ah[s] = *(const uint4*)(&patch[((size_t)s*48 + apx)*8]);

      #pragma unroll
      for (int i = 0; i < 32; ++i) {
        const bf16x8 bf = __builtin_bit_cast(bf16x8, Br[i&7]);
        if (i < 24)
          Br[(i+8)&7] = *(const uint4*)(bp + (size_t)(i+8)*4096);
        #pragma unroll
        for (int r = 0; r < 10; ++r)
          acc[r] = __builtin_amdgcn_mfma_f32_16x16x32_bf16(
              __builtin_bit_cast(bf16x8, Ah[(i+r)%12]), bf, acc[r], 0, 0, 0);
        if (i < 29)
          Ah[(i+12)%12] = *(const uint4*)(&patch[((size_t)(i+12)*48 + apx)*8]);
      }
    }

    float vals[40];
    #pragma unroll
    for (int r = 0; r < 10; ++r)
      #pragma unroll
      for (int k = 0; k < 4; ++k)
        vals[r*4+k] = acc[r][k] + __shfl_xor(acc[r][k], 8);

    float* red = (float*)patch;
    #pragma unroll
    for (int half = 0; half < 2; ++half) {
      __syncthreads();
      #pragma unroll
      for (int u = 0; u < 20; ++u) red[((size_t)wave*64 + lane)*21 + u] = vals[half*20 + u];
      __syncthreads();
      if (wave == 0 && pr < 8) {
        #pragma unroll
        for (int r = 0; r < 5; ++r) {
          #pragma unroll
          for (int k = 0; k < 4; ++k) {
            const int x = x0 + q*4 + k;    // <= 63
            float s = 0.f;
            #pragma unroll
            for (int w = 0; w < 4; ++w) s += red[((size_t)w*64 + lane)*21 + r*4 + k];
            corr_p[(size_t)cb*270400 + ((size_t)(m*8+pr)*65 + (y0 + half*5 + r))*65 + x] = s;
          }
        }
      }
    }
  } else {
    // ======== 5-row tile, rows 60..64 (r8-proven body) ========
    const int y0 = 60;
    const size_t rowbase = ((size_t)(m*4 + cb) * 96 + y0) * 96;
    for (int k = tid; k < 36*48; k += 256) {
      const int rho = k / 48, px = k - (k/48)*48;
      cp16(&satT[(rowbase + (size_t)rho*96 + x0 + px)*8], &patch[(size_t)k*8]);
    }
    asm volatile("s_waitcnt vmcnt(0)" ::: "memory");
    __syncthreads();

    floatx4 acc[5];
    #pragma unroll
    for (int r = 0; r < 5; ++r) acc[r] = (floatx4){0.f, 0.f, 0.f, 0.f};

    #pragma unroll
    for (int jbi = 0; jbi < 2; ++jbi) {
      const int jb = wave*2 + jbi;
      const int apx = pr + jb*4 + q;
      const u16* bp = gP + ((size_t)cb*1024 + (size_t)(jb*4+q))*128 + (size_t)pr*8;

      uint4 Br[8];
      #pragma unroll
      for (int ii = 0; ii < 8; ++ii) Br[ii] = *(const uint4*)(bp + (size_t)ii*4096);
      uint4 Ah[8];
      #pragma unroll
      for (int s = 0; s < 6; ++s) Ah[s] = *(const uint4*)(&patch[((size_t)s*48 + apx)*8]);

      #pragma unroll
      for (int i = 0; i < 32; ++i) {
        if (i < 30)
          Ah[(i+6)&7] = *(const uint4*)(&patch[((size_t)(i+6)*48 + apx)*8]);
        const bf16x8 bf = __builtin_bit_cast(bf16x8, Br[i&7]);
        if (i < 24)
          Br[(i+8)&7] = *(const uint4*)(bp + (size_t)(i+8)*4096);
        #pragma unroll
        for (int r = 0; r < 5; ++r)
          acc[r] = __builtin_amdgcn_mfma_f32_16x16x32_bf16(
              __builtin_bit_cast(bf16x8, Ah[(i+r)&7]), bf, acc[r], 0, 0, 0);
      }
    }

    float vals[20];
    #pragma unroll
    for (int r = 0; r < 5; ++r)
      #pragma unroll
      for (int k = 0; k < 4; ++k)
        vals[r*4+k] = acc[r][k] + __shfl_xor(acc[r][k], 8);

    __syncthreads();
    float* red = (float*)patch;
    #pragma unroll
    for (int u = 0; u < 20; ++u) red[((size_t)wave*64 + lane)*21 + u] = vals[u];
    __syncthreads();
    if (wave == 0 && pr < 8) {
      #pragma unroll
      for (int r = 0; r < 5; ++r) {
        #pragma unroll
        for (int k = 0; k < 4; ++k) {
          const int x = x0 + q*4 + k;
          float s = 0.f;
          #pragma unroll
          for (int w = 0; w < 4; ++w) s += red[((size_t)w*64 + lane)*21 + r*4 + k];
          corr_p[(size_t)cb*270400 + ((size_t)(m*8+pr)*65 + (y0+r))*65 + x] = s;
        }
      }
    }
  }
}

// ---- K3: fused normalize/max/refine (r8/r9-proven). ----
__global__ __launch_bounds__(256) void k_post(
    const float* __restrict__ corr_p, const float* __restrict__ part,
    const float* __restrict__ nrmp, const float* __restrict__ gnrm,
    const int* __restrict__ tm, const float* __restrict__ grd,
    const float* __restrict__ sat, const float* __restrict__ gmask,
    u32* __restrict__ pmaxE, u32* __restrict__ grpcnt,
    u32* __restrict__ candcnt, u64* __restrict__ cand,
    float* __restrict__ out)
{
  __shared__ float red[256];
  __shared__ float s_bcast;
  __shared__ int s_last;
  __shared__ int fidx[128];
  __shared__ u32 fcnt;

  const int bi = blockIdx.x;
  const int m = bi / 40, n = (bi / 5) & 7, yc = bi % 5, g = m*8 + n;
  const int t = threadIdx.x;
  const bool diag = (m == n);

  red[t] = (t < 96) ? nrmp[m*96 + t] : 0.f;
  __syncthreads();
  for (int s = 128; s > 0; s >>= 1) { if (t < s) red[t] += red[t+s]; __syncthreads(); }
  const float srn = 1.f / fmaxf(sqrtf(red[0]), 1e-12f);
  const float grn = 1.f / fmaxf(sqrtf(gnrm[n]), 1e-12f);
  const float cscale = grn * srn, pscale = srn * srn;
  const int method = tm[0];

  const float* cp = corr_p + (size_t)g*4225;
  const float* pp = part + (size_t)m*4225;
  const int i0 = yc*845, i1 = i0 + 845;
  float vv[4];
  float bestv = -3.4e38f;
  #pragma unroll
  for (int k = 0; k < 4; ++k) {
    const int idx = i0 + k*256 + t;
    float v = -3.4e38f;
    if (idx < i1) {
      const float c = cp[idx] + cp[idx+270400] + cp[idx+540800] + cp[idx+811200];
      const float pt = pp[idx] * pscale;
      float denom = (method == 0) ? sqrtf(pt) : pt;
      denom = fmaxf(denom, 1e-12f);
      v = c * cscale / denom;
    }
    vv[k] = v;
    bestv = fmaxf(bestv, v);
  }
  __syncthreads();
  red[t] = bestv; __syncthreads();
  for (int s = 128; s > 0; s >>= 1) { if (t < s) red[t] = fmaxf(red[t], red[t+s]); __syncthreads(); }
  if (t == 0) { s_bcast = red[0]; atomicExch(&pmaxE[bi], encf(red[0])); }
  __syncthreads();
  if (diag) {
    const float lthr = s_bcast - 3e-3f;
    #pragma unroll
    for (int k = 0; k < 4; ++k) {
      const int idx = i0 + k*256 + t;
      if (idx < i1 && vv[k] >= lthr) {
        const u32 s = atomicAdd(&candcnt[n], 1u);
        if (s < 128)
          atomicExch(&cand[n*128 + s],
                     ((u64)__builtin_bit_cast(u32, vv[k]) << 32) | (u32)idx);
      }
    }
  }
  __syncthreads();
  if (t == 0) s_last = (atomicAdd(&grpcnt[g], 1u) == 4u) ? 1 : 0;
  __syncthreads();
  if (!s_last) return;

  if (t == 0) {
    float gm = -3.4e38f;
    #pragma unroll
    for (int k = 0; k < 5; ++k) gm = fmaxf(gm, decf(atomicOr(&pmaxE[g*5 + k], 0u)));
    out[g] = gm;
    s_bcast = gm;
  }
  __syncthreads();
  if (!diag) return;

  const float gmax = s_bcast;
  const float thr = gmax - 3e-3f;
  if (t == 0) fcnt = 0u;
  __syncthreads();
  u32 nc = atomicAdd(&candcnt[n], 0u); if (nc > 128) nc = 128;
  if (t < (int)nc) {
    const u64 pk = atomicAdd(&cand[n*128 + t], 0ULL);
    const float vf = __builtin_bit_cast(float, (u32)(pk >> 32));
    const int idx = (int)(u32)pk;
    if (vf >= thr) { const u32 s = atomicAdd(&fcnt, 1u); fidx[s] = idx; }
  }
  __syncthreads();
  if (t == 0 && fcnt == 0u) { fidx[0] = 0; fcnt = 1u; }
  __syncthreads();
  const int nf = (int)fcnt;

  __shared__ float sbest; __shared__ int sbix;
  if (t == 0) { sbest = -3.4e38f; sbix = 0x7FFFFFFF; }
  __syncthreads();
  const int c = t >> 3, s8 = t & 7;
  for (int ci = 0; ci < nf; ++ci) {
    const int idx = fidx[ci];
    const int y = idx / 65, x = idx - y*65;
    float a = 0.f;
    #pragma unroll
    for (int ii = 0; ii < 4; ++ii) {
      const int i = s8 + ii*8;
      const float* gr = grd + ((size_t)n*32 + c)*1024 + i*32;
      const float* sr = sat + (((size_t)n*32 + c)*128 + (16 + y + i))*128 + (16 + x);
      #pragma unroll
      for (int j = 0; j < 32; ++j) a += gr[j] * sr[j];
    }
    red[t] = a; __syncthreads();
    for (int st = 128; st > 0; st >>= 1) { if (t < st) red[t] += red[t+st]; __syncthreads(); }
    if (t == 0) {
      const float pt = part[(size_t)n*4225 + idx] * pscale;
      float denom = (method == 0) ? sqrtf(pt) : pt;
      denom = fmaxf(denom, 1e-12f);
      const float v = red[0] * cscale / denom;
      if (v > sbest || (v == sbest && idx < sbix)) { sbest = v; sbix = idx; }
    }
    __syncthreads();
  }
  const int bix = sbix;
  const int ph = bix / 65, pw = bix - (bix/65)*65;
  for (int p = t; p < 9216; p += 256) {
    const int yy = p / 96, xx = p - yy*96;
    float val = 0.f;
    if (yy >= ph && yy < ph+32 && xx >= pw && xx < pw+32)
      val = gmask[n*1024 + (yy-ph)*32 + (xx-pw)];
    out[64 + (size_t)n*9216 + p] = val;
  }
}

extern "C" void kernel_launch(void* const* d_in, const int* in_sizes, int n_in,
                              void* d_out, int out_size, void* d_ws, size_t ws_size,
                              hipStream_t stream) {
  const float* grd = (const float*)d_in[0];
  const float* sat = (const float*)d_in[1];
  const int*   tm  = (const int*)d_in[2];
  float* out = (float*)d_out;
  char* ws = (char*)d_ws;

  float* corrp = (float*)(ws + OFF_CORRP);
  u16*   sTh   = (u16*)(ws + OFF_SATT);
  u16*   gP    = (u16*)(ws + OFF_GRDP);
  float* s2    = (float*)(ws + OFF_S2);
  float* part  = (float*)(ws + OFF_PART);
  float* nrmp  = (float*)(ws + OFF_NRMP);
  float* gnrm  = (float*)(ws + OFF_GNRM);
  float* gmask = (float*)(ws + OFF_MASK);
  u32*   pmaxE = (u32*)(ws + OFF_PMAX);
  u32*   cnts  = (u32*)(ws + OFF_CNT);
  u64*   cand  = (u64*)(ws + OFF_CAND);

  k_prep<<<777,  256, 0, stream>>>(grd, sat, sTh, gP, s2, nrmp, gnrm, gmask, cnts);
  k_conv<<<1128, 256, 0, stream>>>(sTh, gP, s2, corrp, part);
  k_post<<<320,  256, 0, stream>>>(corrp, part, nrmp, gnrm, tm, grd, sat, gmask,
                                   pmaxE, cnts, cnts + 64, cand, out);
}